// Round 1
// baseline (6452.596 us; speedup 1.0000x reference)
//
#include <hip/hip_runtime.h>
#include <math.h>

namespace {

constexpr int Bc = 4, Tc = 1024, Cch = 768, Hc = 12, Dc = 64, KSEL = 10;
constexpr size_t BTC    = (size_t)Bc * Tc * Cch;        // 3,145,728
constexpr size_t PROBSN = (size_t)Bc * Hc * Tc * Tc;    // 50,331,648

// ---------------------------------------------------------------------------
// K1: QKV projection.  out[z][bh][t][d] = hidden[m][:] @ W[:, h*64+d] + bias
// f32 GEMM, M=4096, N=768, K=768.  Tile 64(M) x 128(N), BK=16, 256 threads,
// 4x8 per thread.  z in {0,1,2} selects (Wq,bq),(Wk,bk),(Wv,bv).
// ---------------------------------------------------------------------------
__global__ __launch_bounds__(256) void qkv_gemm(
    const float* __restrict__ hid,
    const float* __restrict__ Wq, const float* __restrict__ bq,
    const float* __restrict__ Wk, const float* __restrict__ bk,
    const float* __restrict__ Wv, const float* __restrict__ bv,
    float* __restrict__ qkv)
{
  const int z = blockIdx.z;
  const float* __restrict__ W    = (z == 0) ? Wq : (z == 1) ? Wk : Wv;
  const float* __restrict__ bias = (z == 0) ? bq : (z == 1) ? bk : bv;
  float* __restrict__ out = qkv + (size_t)z * BTC;

  const int m0 = blockIdx.y * 64;
  const int n0 = blockIdx.x * 128;

  __shared__ float aT[16][68];    // [k][m], padded
  __shared__ float bN[16][132];   // [k][n], padded

  const int t  = threadIdx.x;
  const int tn = t & 15;          // n-group: cols 4*tn..+3 and 64+4*tn..+3
  const int tq = t >> 4;          // m-group: rows 4*tq..+3

  float acc[4][8];
  #pragma unroll
  for (int i = 0; i < 4; ++i) {
    #pragma unroll
    for (int j = 0; j < 8; ++j) acc[i][j] = 0.f;
  }

  for (int k0 = 0; k0 < Cch; k0 += 16) {
    __syncthreads();
    {   // stage A 64x16 transposed: 1024 f32, 1 float4/thread
      const int r = t >> 2, c = t & 3;
      const float4 v = *(const float4*)&hid[(size_t)(m0 + r) * Cch + k0 + 4*c];
      aT[4*c + 0][r] = v.x; aT[4*c + 1][r] = v.y;
      aT[4*c + 2][r] = v.z; aT[4*c + 3][r] = v.w;
    }
    #pragma unroll
    for (int p = 0; p < 2; ++p) {   // stage B 16x128: 2 float4/thread
      const int id = t + 256*p;
      const int kk = id >> 5, nc = id & 31;
      const float4 v = *(const float4*)&W[(size_t)(k0 + kk) * Cch + n0 + 4*nc];
      *(float4*)&bN[kk][4*nc] = v;
    }
    __syncthreads();
    #pragma unroll
    for (int kk = 0; kk < 16; ++kk) {
      const float4 a  = *(const float4*)&aT[kk][4*tq];
      const float4 b0 = *(const float4*)&bN[kk][4*tn];
      const float4 b1 = *(const float4*)&bN[kk][64 + 4*tn];
      const float av[4] = {a.x, a.y, a.z, a.w};
      const float bw[8] = {b0.x, b0.y, b0.z, b0.w, b1.x, b1.y, b1.z, b1.w};
      #pragma unroll
      for (int qi = 0; qi < 4; ++qi) {
        #pragma unroll
        for (int ni = 0; ni < 8; ++ni) acc[qi][ni] += av[qi] * bw[ni];
      }
    }
  }

  const float4 bb0 = *(const float4*)&bias[n0 + 4*tn];
  const float4 bb1 = *(const float4*)&bias[n0 + 64 + 4*tn];
  const int h0 = n0 >> 6;    // first of the two heads this n-tile covers
  #pragma unroll
  for (int qi = 0; qi < 4; ++qi) {
    const int m = m0 + 4*tq + qi;
    const int b = m >> 10, tt = m & 1023;
    float4 o0, o1;
    o0.x = acc[qi][0] + bb0.x; o0.y = acc[qi][1] + bb0.y;
    o0.z = acc[qi][2] + bb0.z; o0.w = acc[qi][3] + bb0.w;
    o1.x = acc[qi][4] + bb1.x; o1.y = acc[qi][5] + bb1.y;
    o1.z = acc[qi][6] + bb1.z; o1.w = acc[qi][7] + bb1.w;
    *(float4*)&out[(((size_t)(b*Hc + h0    ))*Tc + tt)*Dc + 4*tn] = o0;
    *(float4*)&out[(((size_t)(b*Hc + h0 + 1))*Tc + tt)*Dc + 4*tn] = o1;
  }
}

// ---------------------------------------------------------------------------
// K2: fused scores + softmax + UCB top-k + renorm + count update.
// Block = 512 threads (8 waves), 32 q-rows per block; wave w owns rows
// 4w..4w+3; lane owns k = lane + 64*w16 (w16=0..15) -> whole 1024-wide row
// lives in the wave's registers; fully coalesced global I/O.
// ---------------------------------------------------------------------------
__global__ __launch_bounds__(512) void attn_ucb(
    const float* __restrict__ qkv,
    const float* __restrict__ count_in,
    const int*   __restrict__ counter_p,
    const int*   __restrict__ ucb_p,
    float* __restrict__ probs_out,
    float* __restrict__ count_out)
{
  const int bh = blockIdx.y;
  const int q0 = blockIdx.x * 32;
  const float* __restrict__ Qm = qkv;
  const float* __restrict__ Km = qkv + BTC;

  __shared__ float kN[128][68];   // K chunk [k][d], padded (8 lanes/4-bank grp)
  __shared__ float qN[32][68];    // Q tile  [r][d]

  const int t    = threadIdx.x;
  const int lane = t & 63;
  const int wv   = t >> 6;        // wave id 0..7

  {   // stage Q tile: 32x64 = 2048 f32, 1 float4/thread
    const int dc = t & 15, r = t >> 4;
    const float4 v = *(const float4*)&Qm[((size_t)bh*Tc + q0 + r)*Dc + 4*dc];
    *(float4*)&qN[r][4*dc] = v;
  }

  float acc[4][16];               // [qi][w16], k = lane + 64*w16
  #pragma unroll
  for (int i = 0; i < 4; ++i) {
    #pragma unroll
    for (int w = 0; w < 16; ++w) acc[i][w] = 0.f;
  }

  #pragma unroll
  for (int j = 0; j < 8; ++j) {   // 8 chunks of 128 k-rows
    __syncthreads();
    {
      const int dc = t & 15, kr = t >> 4;
      #pragma unroll
      for (int p = 0; p < 4; ++p) {
        const int row = kr + 32*p;
        const float4 v =
            *(const float4*)&Km[((size_t)bh*Tc + 128*j + row)*Dc + 4*dc];
        *(float4*)&kN[row][4*dc] = v;
      }
    }
    __syncthreads();
    #pragma unroll
    for (int d4 = 0; d4 < 16; ++d4) {
      float4 qv[4];
      #pragma unroll
      for (int qi = 0; qi < 4; ++qi)
        qv[qi] = *(const float4*)&qN[4*wv + qi][4*d4];
      #pragma unroll
      for (int c = 0; c < 2; ++c) {
        const float4 kv = *(const float4*)&kN[lane + 64*c][4*d4];
        #pragma unroll
        for (int qi = 0; qi < 4; ++qi)
          acc[qi][2*j + c] += qv[qi].x*kv.x + qv[qi].y*kv.y
                            + qv[qi].z*kv.z + qv[qi].w*kv.w;
      }
    }
  }

  // ---- phase 3: per-row softmax + UCB, registers + shfl only ----
  const int  counter = counter_p[0];
  const int  ucb     = ucb_p[0];
  const bool do_ucb  = (ucb != 0) && (counter >= 1000);
  const float lt     = do_ucb ? (float)log((double)counter) : 0.f;

  #pragma unroll
  for (int qi = 0; qi < 4; ++qi) {
    const int    row = q0 + 4*wv + qi;
    const size_t rb  = ((size_t)bh*Tc + row) * Tc;

    float s[16];
    #pragma unroll
    for (int w = 0; w < 16; ++w) s[w] = acc[qi][w] * 0.125f;  // /sqrt(64)

    float mx = -INFINITY;
    #pragma unroll
    for (int w = 0; w < 16; ++w) mx = fmaxf(mx, s[w]);
    #pragma unroll
    for (int off = 32; off > 0; off >>= 1) mx = fmaxf(mx, __shfl_xor(mx, off));

    float sum = 0.f;
    #pragma unroll
    for (int w = 0; w < 16; ++w) { s[w] = expf(s[w] - mx); sum += s[w]; }
    #pragma unroll
    for (int off = 32; off > 0; off >>= 1) sum += __shfl_xor(sum, off);

    #pragma unroll
    for (int w = 0; w < 16; ++w) s[w] = s[w] / sum;           // att

    float cnt[16];
    #pragma unroll
    for (int w = 0; w < 16; ++w) cnt[w] = count_in[rb + lane + 64*w];

    if (do_ucb) {
      float u[16];
      #pragma unroll
      for (int w = 0; w < 16; ++w)
        u[w] = s[w] + sqrtf(lt / (cnt[w] + 1e-8f));

      unsigned sel = 0u;
      for (int r = 0; r < KSEL; ++r) {
        float bv = -INFINITY; int bk = 1 << 30;
        #pragma unroll
        for (int w = 0; w < 16; ++w) {
          if (!((sel >> w) & 1u)) {
            const int kk = lane + 64*w;
            if (u[w] > bv || (u[w] == bv && kk < bk)) { bv = u[w]; bk = kk; }
          }
        }
        #pragma unroll
        for (int off = 32; off > 0; off >>= 1) {
          const float ov = __shfl_xor(bv, off);
          const int   ok = __shfl_xor(bk, off);
          if (ov > bv || (ov == bv && ok < bk)) { bv = ov; bk = ok; }
        }
        if ((bk & 63) == lane) sel |= 1u << (bk >> 6);
      }

      float ssum = 0.f;
      #pragma unroll
      for (int w = 0; w < 16; ++w) if ((sel >> w) & 1u) ssum += s[w];
      #pragma unroll
      for (int off = 32; off > 0; off >>= 1) ssum += __shfl_xor(ssum, off);
      const float denom = ssum + 1e-8f;

      #pragma unroll
      for (int w = 0; w < 16; ++w) {
        const bool sb = (sel >> w) & 1u;
        probs_out[rb + lane + 64*w] = sb ? (s[w] / denom) : 0.0f;
        count_out[rb + lane + 64*w] = cnt[w] + (sb ? 1.0f : 0.0f);
      }
    } else {
      #pragma unroll
      for (int w = 0; w < 16; ++w) {
        probs_out[rb + lane + 64*w] = s[w];
        count_out[rb + lane + 64*w] = cnt[w];
      }
    }
  }
}

// ---------------------------------------------------------------------------
// K3: ctx = probs @ V per (b,h).  M=1024, N=64, K=1024.  Tile 64x64, BK=32,
// 256 threads, 4x4 per thread.  Writes ctx as [B][T][C] (head-interleaved).
// ---------------------------------------------------------------------------
__global__ __launch_bounds__(256) void pv_gemm(
    const float* __restrict__ probs,
    const float* __restrict__ Vm,
    float* __restrict__ ctx)
{
  const int bh = blockIdx.y;
  const int q0 = blockIdx.x * 64;
  const int b = bh / Hc, h = bh % Hc;

  __shared__ float aT[32][68];   // probs^T [k][q]
  __shared__ float vN[32][68];   // V [k][d]

  const int t  = threadIdx.x;
  const int tn = t & 15;
  const int tq = t >> 4;

  float acc[4][4];
  #pragma unroll
  for (int i = 0; i < 4; ++i) {
    #pragma unroll
    for (int j = 0; j < 4; ++j) acc[i][j] = 0.f;
  }

  for (int k0 = 0; k0 < Tc; k0 += 32) {
    __syncthreads();
    #pragma unroll
    for (int p = 0; p < 2; ++p) {   // stage probs 64x32 transposed
      const int id = t + 256*p;
      const int r = id >> 3, c = id & 7;
      const float4 v =
          *(const float4*)&probs[((size_t)bh*Tc + q0 + r)*Tc + k0 + 4*c];
      aT[4*c + 0][r] = v.x; aT[4*c + 1][r] = v.y;
      aT[4*c + 2][r] = v.z; aT[4*c + 3][r] = v.w;
    }
    #pragma unroll
    for (int p = 0; p < 2; ++p) {   // stage V 32x64
      const int id = t + 256*p;
      const int kk = id >> 4, dc = id & 15;
      const float4 v = *(const float4*)&Vm[((size_t)bh*Tc + k0 + kk)*Dc + 4*dc];
      *(float4*)&vN[kk][4*dc] = v;
    }
    __syncthreads();
    #pragma unroll
    for (int kk = 0; kk < 32; ++kk) {
      const float4 a  = *(const float4*)&aT[kk][4*tq];
      const float4 vv = *(const float4*)&vN[kk][4*tn];
      const float av[4] = {a.x, a.y, a.z, a.w};
      const float bw[4] = {vv.x, vv.y, vv.z, vv.w};
      #pragma unroll
      for (int qi = 0; qi < 4; ++qi) {
        #pragma unroll
        for (int ni = 0; ni < 4; ++ni) acc[qi][ni] += av[qi] * bw[ni];
      }
    }
  }

  #pragma unroll
  for (int qi = 0; qi < 4; ++qi) {
    const int tt = q0 + 4*tq + qi;
    float4 o;
    o.x = acc[qi][0]; o.y = acc[qi][1]; o.z = acc[qi][2]; o.w = acc[qi][3];
    *(float4*)&ctx[((size_t)b*Tc + tt)*Cch + h*Dc + 4*tn] = o;
  }
}

// ---------------------------------------------------------------------------
// K4: out = ctx @ Wo + bo.  Same shape/tiling as K1, plain [M][N] output.
// ---------------------------------------------------------------------------
__global__ __launch_bounds__(256) void out_gemm(
    const float* __restrict__ A,
    const float* __restrict__ W,
    const float* __restrict__ bias,
    float* __restrict__ out)
{
  const int m0 = blockIdx.y * 64;
  const int n0 = blockIdx.x * 128;

  __shared__ float aT[16][68];
  __shared__ float bN[16][132];

  const int t  = threadIdx.x;
  const int tn = t & 15;
  const int tq = t >> 4;

  float acc[4][8];
  #pragma unroll
  for (int i = 0; i < 4; ++i) {
    #pragma unroll
    for (int j = 0; j < 8; ++j) acc[i][j] = 0.f;
  }

  for (int k0 = 0; k0 < Cch; k0 += 16) {
    __syncthreads();
    {
      const int r = t >> 2, c = t & 3;
      const float4 v = *(const float4*)&A[(size_t)(m0 + r) * Cch + k0 + 4*c];
      aT[4*c + 0][r] = v.x; aT[4*c + 1][r] = v.y;
      aT[4*c + 2][r] = v.z; aT[4*c + 3][r] = v.w;
    }
    #pragma unroll
    for (int p = 0; p < 2; ++p) {
      const int id = t + 256*p;
      const int kk = id >> 5, nc = id & 31;
      const float4 v = *(const float4*)&W[(size_t)(k0 + kk) * Cch + n0 + 4*nc];
      *(float4*)&bN[kk][4*nc] = v;
    }
    __syncthreads();
    #pragma unroll
    for (int kk = 0; kk < 16; ++kk) {
      const float4 a  = *(const float4*)&aT[kk][4*tq];
      const float4 b0 = *(const float4*)&bN[kk][4*tn];
      const float4 b1 = *(const float4*)&bN[kk][64 + 4*tn];
      const float av[4] = {a.x, a.y, a.z, a.w};
      const float bw[8] = {b0.x, b0.y, b0.z, b0.w, b1.x, b1.y, b1.z, b1.w};
      #pragma unroll
      for (int qi = 0; qi < 4; ++qi) {
        #pragma unroll
        for (int ni = 0; ni < 8; ++ni) acc[qi][ni] += av[qi] * bw[ni];
      }
    }
  }

  const float4 bb0 = *(const float4*)&bias[n0 + 4*tn];
  const float4 bb1 = *(const float4*)&bias[n0 + 64 + 4*tn];
  #pragma unroll
  for (int qi = 0; qi < 4; ++qi) {
    const int m = m0 + 4*tq + qi;
    float4 o0, o1;
    o0.x = acc[qi][0] + bb0.x; o0.y = acc[qi][1] + bb0.y;
    o0.z = acc[qi][2] + bb0.z; o0.w = acc[qi][3] + bb0.w;
    o1.x = acc[qi][4] + bb1.x; o1.y = acc[qi][5] + bb1.y;
    o1.z = acc[qi][6] + bb1.z; o1.w = acc[qi][7] + bb1.w;
    *(float4*)&out[(size_t)m * Cch + n0 + 4*tn]      = o0;
    *(float4*)&out[(size_t)m * Cch + n0 + 64 + 4*tn] = o1;
  }
}

} // anonymous namespace

// ---------------------------------------------------------------------------
extern "C" void kernel_launch(void* const* d_in, const int* in_sizes, int n_in,
                              void* d_out, int out_size, void* d_ws, size_t ws_size,
                              hipStream_t stream) {
  (void)in_sizes; (void)n_in; (void)out_size; (void)ws_size;

  const float* hid  = (const float*)d_in[0];
  const float* cnt  = (const float*)d_in[1];
  const float* Wq   = (const float*)d_in[2];
  const float* bq   = (const float*)d_in[3];
  const float* Wk   = (const float*)d_in[4];
  const float* bk   = (const float*)d_in[5];
  const float* Wv   = (const float*)d_in[6];
  const float* bv   = (const float*)d_in[7];
  const float* Wo   = (const float*)d_in[8];
  const float* bo   = (const float*)d_in[9];
  const int* counter = (const int*)d_in[10];
  const int* ucb     = (const int*)d_in[11];

  float* out       = (float*)d_out;          // [B,T,C]
  float* probs     = out + BTC;              // [B,H,T,T]
  float* count_out = probs + PROBSN;         // [B,H,T,T]

  // workspace: Q | K | V | ctx, each BTC floats (needs 50.3 MB)
  float* ws = (float*)d_ws;

  qkv_gemm<<<dim3(Cch/128, (Bc*Tc)/64, 3), 256, 0, stream>>>(
      hid, Wq, bq, Wk, bk, Wv, bv, ws);

  attn_ucb<<<dim3(Tc/32, Bc*Hc), 512, 0, stream>>>(
      ws, cnt, counter, ucb, probs, count_out);

  pv_gemm<<<dim3(Tc/64, Bc*Hc), 256, 0, stream>>>(
      probs, ws + 2*BTC, ws + 3*BTC);

  out_gemm<<<dim3(Cch/128, (Bc*Tc)/64), 256, 0, stream>>>(
      ws + 3*BTC, Wo, bo, out);
}

// Round 2
// 1015.248 us; speedup vs baseline: 6.3557x; 6.3557x over previous
//
#include <hip/hip_runtime.h>
#include <math.h>

namespace {

constexpr int Bc = 4, Tc = 1024, Cch = 768, Hc = 12, Dc = 64, KSEL = 10;
constexpr size_t BTC    = (size_t)Bc * Tc * Cch;        // 3,145,728
constexpr size_t PROBSN = (size_t)Bc * Hc * Tc * Tc;    // 50,331,648

// ---------------------------------------------------------------------------
// K1: QKV projection.  out[z][bh][t][d] = hidden[m][:] @ W[:, h*64+d] + bias
// f32 GEMM, M=4096, N=768, K=768.  Tile 64(M) x 128(N), BK=16, 256 threads,
// 4x8 per thread.  z in {0,1,2} selects (Wq,bq),(Wk,bk),(Wv,bv).
// ---------------------------------------------------------------------------
__global__ __launch_bounds__(256) void qkv_gemm(
    const float* __restrict__ hid,
    const float* __restrict__ Wq, const float* __restrict__ bq,
    const float* __restrict__ Wk, const float* __restrict__ bk,
    const float* __restrict__ Wv, const float* __restrict__ bv,
    float* __restrict__ qkv)
{
  const int z = blockIdx.z;
  const float* __restrict__ W    = (z == 0) ? Wq : (z == 1) ? Wk : Wv;
  const float* __restrict__ bias = (z == 0) ? bq : (z == 1) ? bk : bv;
  float* __restrict__ out = qkv + (size_t)z * BTC;

  const int m0 = blockIdx.y * 64;
  const int n0 = blockIdx.x * 128;

  __shared__ float aT[16][68];    // [k][m], padded
  __shared__ float bN[16][132];   // [k][n], padded

  const int t  = threadIdx.x;
  const int tn = t & 15;          // n-group: cols 4*tn..+3 and 64+4*tn..+3
  const int tq = t >> 4;          // m-group: rows 4*tq..+3

  float acc[4][8];
  #pragma unroll
  for (int i = 0; i < 4; ++i) {
    #pragma unroll
    for (int j = 0; j < 8; ++j) acc[i][j] = 0.f;
  }

  for (int k0 = 0; k0 < Cch; k0 += 16) {
    __syncthreads();
    {   // stage A 64x16 transposed: 1024 f32, 1 float4/thread
      const int r = t >> 2, c = t & 3;
      const float4 v = *(const float4*)&hid[(size_t)(m0 + r) * Cch + k0 + 4*c];
      aT[4*c + 0][r] = v.x; aT[4*c + 1][r] = v.y;
      aT[4*c + 2][r] = v.z; aT[4*c + 3][r] = v.w;
    }
    #pragma unroll
    for (int p = 0; p < 2; ++p) {   // stage B 16x128: 2 float4/thread
      const int id = t + 256*p;
      const int kk = id >> 5, nc = id & 31;
      const float4 v = *(const float4*)&W[(size_t)(k0 + kk) * Cch + n0 + 4*nc];
      *(float4*)&bN[kk][4*nc] = v;
    }
    __syncthreads();
    #pragma unroll
    for (int kk = 0; kk < 16; ++kk) {
      const float4 a  = *(const float4*)&aT[kk][4*tq];
      const float4 b0 = *(const float4*)&bN[kk][4*tn];
      const float4 b1 = *(const float4*)&bN[kk][64 + 4*tn];
      const float av[4] = {a.x, a.y, a.z, a.w};
      const float bw[8] = {b0.x, b0.y, b0.z, b0.w, b1.x, b1.y, b1.z, b1.w};
      #pragma unroll
      for (int qi = 0; qi < 4; ++qi) {
        #pragma unroll
        for (int ni = 0; ni < 8; ++ni) acc[qi][ni] += av[qi] * bw[ni];
      }
    }
  }

  const float4 bb0 = *(const float4*)&bias[n0 + 4*tn];
  const float4 bb1 = *(const float4*)&bias[n0 + 64 + 4*tn];
  const int h0 = n0 >> 6;    // first of the two heads this n-tile covers
  #pragma unroll
  for (int qi = 0; qi < 4; ++qi) {
    const int m = m0 + 4*tq + qi;
    const int b = m >> 10, tt = m & 1023;
    float4 o0, o1;
    o0.x = acc[qi][0] + bb0.x; o0.y = acc[qi][1] + bb0.y;
    o0.z = acc[qi][2] + bb0.z; o0.w = acc[qi][3] + bb0.w;
    o1.x = acc[qi][4] + bb1.x; o1.y = acc[qi][5] + bb1.y;
    o1.z = acc[qi][6] + bb1.z; o1.w = acc[qi][7] + bb1.w;
    *(float4*)&out[(((size_t)(b*Hc + h0    ))*Tc + tt)*Dc + 4*tn] = o0;
    *(float4*)&out[(((size_t)(b*Hc + h0 + 1))*Tc + tt)*Dc + 4*tn] = o1;
  }
}

// ---------------------------------------------------------------------------
// K2: fused scores + softmax + UCB top-k + renorm + count update.
// Block = 512 threads (8 waves); wave w owns rows 2w..2w+1 (16 rows/block);
// lane owns k = lane + 64*w16 (w16=0..15) -> whole 1024-wide row in the
// wave's registers; fully coalesced global I/O.
// Register budget (the round-1 spill fix): acc[2][16]=32 VGPRs live across
// the score loop; phase 3 is `#pragma unroll 1` per row so only one row's
// s[16]+cnt[16]+u[16] (48 VGPRs) is live at a time -> peak ~100 < 128.
// ---------------------------------------------------------------------------
__global__ __launch_bounds__(512) void attn_ucb(
    const float* __restrict__ qkv,
    const float* __restrict__ count_in,
    const int*   __restrict__ counter_p,
    const int*   __restrict__ ucb_p,
    float* __restrict__ probs_out,
    float* __restrict__ count_out)
{
  const int bh = blockIdx.y;
  const int q0 = blockIdx.x * 16;
  const float* __restrict__ Qm = qkv;
  const float* __restrict__ Km = qkv + BTC;

  __shared__ float kN[128][68];   // K chunk [k][d], padded
  __shared__ float qN[16][68];    // Q tile  [r][d]

  const int t    = threadIdx.x;
  const int lane = t & 63;
  const int wv   = t >> 6;        // wave id 0..7

  if (t < 256) {   // stage Q tile: 16x64 = 1024 f32, 1 float4/thread
    const int dc = t & 15, r = t >> 4;
    const float4 v = *(const float4*)&Qm[((size_t)bh*Tc + q0 + r)*Dc + 4*dc];
    *(float4*)&qN[r][4*dc] = v;
  }

  float acc[2][16];               // [qi][w16], k = lane + 64*w16
  #pragma unroll
  for (int i = 0; i < 2; ++i) {
    #pragma unroll
    for (int w = 0; w < 16; ++w) acc[i][w] = 0.f;
  }

  #pragma unroll 1
  for (int j = 0; j < 8; ++j) {   // 8 chunks of 128 k-rows
    __syncthreads();
    {
      const int dc = t & 15, kr = t >> 4;
      #pragma unroll
      for (int p = 0; p < 4; ++p) {
        const int row = kr + 32*p;
        const float4 v =
            *(const float4*)&Km[((size_t)bh*Tc + 128*j + row)*Dc + 4*dc];
        *(float4*)&kN[row][4*dc] = v;
      }
    }
    __syncthreads();
    #pragma unroll
    for (int d4 = 0; d4 < 16; ++d4) {
      const float4 q0v = *(const float4*)&qN[2*wv    ][4*d4];
      const float4 q1v = *(const float4*)&qN[2*wv + 1][4*d4];
      #pragma unroll
      for (int c = 0; c < 2; ++c) {
        const float4 kv = *(const float4*)&kN[lane + 64*c][4*d4];
        acc[0][2*j + c] += q0v.x*kv.x + q0v.y*kv.y + q0v.z*kv.z + q0v.w*kv.w;
        acc[1][2*j + c] += q1v.x*kv.x + q1v.y*kv.y + q1v.z*kv.z + q1v.w*kv.w;
      }
    }
  }

  // ---- phase 3: per-row softmax + UCB, registers + shfl only ----
  const int  counter = counter_p[0];
  const int  ucb     = ucb_p[0];
  const bool do_ucb  = (ucb != 0) && (counter >= 1000);
  const float lt     = do_ucb ? logf((float)counter) : 0.f;

  #pragma unroll 1
  for (int qi = 0; qi < 2; ++qi) {
    const int    row = q0 + 2*wv + qi;
    const size_t rb  = ((size_t)bh*Tc + row) * Tc;

    float s[16];
    #pragma unroll
    for (int w = 0; w < 16; ++w) s[w] = acc[qi][w] * 0.125f;  // /sqrt(64)

    float mx = -INFINITY;
    #pragma unroll
    for (int w = 0; w < 16; ++w) mx = fmaxf(mx, s[w]);
    #pragma unroll
    for (int off = 32; off > 0; off >>= 1) mx = fmaxf(mx, __shfl_xor(mx, off));

    float sum = 0.f;
    #pragma unroll
    for (int w = 0; w < 16; ++w) { s[w] = expf(s[w] - mx); sum += s[w]; }
    #pragma unroll
    for (int off = 32; off > 0; off >>= 1) sum += __shfl_xor(sum, off);

    #pragma unroll
    for (int w = 0; w < 16; ++w) s[w] = s[w] / sum;           // att

    float cnt[16];
    #pragma unroll
    for (int w = 0; w < 16; ++w) cnt[w] = count_in[rb + lane + 64*w];

    if (do_ucb) {
      float u[16];
      #pragma unroll
      for (int w = 0; w < 16; ++w)
        u[w] = s[w] + sqrtf(lt / (cnt[w] + 1e-8f));

      unsigned sel = 0u;
      #pragma unroll 1
      for (int r = 0; r < KSEL; ++r) {
        float bv = -INFINITY; int bk = 1 << 30;
        #pragma unroll
        for (int w = 0; w < 16; ++w) {
          if (!((sel >> w) & 1u)) {
            const int kk = lane + 64*w;
            if (u[w] > bv || (u[w] == bv && kk < bk)) { bv = u[w]; bk = kk; }
          }
        }
        #pragma unroll
        for (int off = 32; off > 0; off >>= 1) {
          const float ov = __shfl_xor(bv, off);
          const int   ok = __shfl_xor(bk, off);
          if (ov > bv || (ov == bv && ok < bk)) { bv = ov; bk = ok; }
        }
        if ((bk & 63) == lane) sel |= 1u << (bk >> 6);
      }

      float ssum = 0.f;
      #pragma unroll
      for (int w = 0; w < 16; ++w) if ((sel >> w) & 1u) ssum += s[w];
      #pragma unroll
      for (int off = 32; off > 0; off >>= 1) ssum += __shfl_xor(ssum, off);
      const float denom = ssum + 1e-8f;

      #pragma unroll
      for (int w = 0; w < 16; ++w) {
        const bool sb = (sel >> w) & 1u;
        probs_out[rb + lane + 64*w] = sb ? (s[w] / denom) : 0.0f;
        count_out[rb + lane + 64*w] = cnt[w] + (sb ? 1.0f : 0.0f);
      }
    } else {
      #pragma unroll
      for (int w = 0; w < 16; ++w) {
        probs_out[rb + lane + 64*w] = s[w];
        count_out[rb + lane + 64*w] = cnt[w];
      }
    }
  }
}

// ---------------------------------------------------------------------------
// K3: ctx = probs @ V per (b,h).  M=1024, N=64, K=1024.  Tile 64x64, BK=32,
// 256 threads, 4x4 per thread.  Writes ctx as [B][T][C] (head-interleaved).
// ---------------------------------------------------------------------------
__global__ __launch_bounds__(256) void pv_gemm(
    const float* __restrict__ probs,
    const float* __restrict__ Vm,
    float* __restrict__ ctx)
{
  const int bh = blockIdx.y;
  const int q0 = blockIdx.x * 64;
  const int b = bh / Hc, h = bh % Hc;

  __shared__ float aT[32][68];   // probs^T [k][q]
  __shared__ float vN[32][68];   // V [k][d]

  const int t  = threadIdx.x;
  const int tn = t & 15;
  const int tq = t >> 4;

  float acc[4][4];
  #pragma unroll
  for (int i = 0; i < 4; ++i) {
    #pragma unroll
    for (int j = 0; j < 4; ++j) acc[i][j] = 0.f;
  }

  for (int k0 = 0; k0 < Tc; k0 += 32) {
    __syncthreads();
    #pragma unroll
    for (int p = 0; p < 2; ++p) {   // stage probs 64x32 transposed
      const int id = t + 256*p;
      const int r = id >> 3, c = id & 7;
      const float4 v =
          *(const float4*)&probs[((size_t)bh*Tc + q0 + r)*Tc + k0 + 4*c];
      aT[4*c + 0][r] = v.x; aT[4*c + 1][r] = v.y;
      aT[4*c + 2][r] = v.z; aT[4*c + 3][r] = v.w;
    }
    #pragma unroll
    for (int p = 0; p < 2; ++p) {   // stage V 32x64
      const int id = t + 256*p;
      const int kk = id >> 4, dc = id & 15;
      const float4 v = *(const float4*)&Vm[((size_t)bh*Tc + k0 + kk)*Dc + 4*dc];
      *(float4*)&vN[kk][4*dc] = v;
    }
    __syncthreads();
    #pragma unroll
    for (int kk = 0; kk < 32; ++kk) {
      const float4 a  = *(const float4*)&aT[kk][4*tq];
      const float4 vv = *(const float4*)&vN[kk][4*tn];
      const float av[4] = {a.x, a.y, a.z, a.w};
      const float bw[4] = {vv.x, vv.y, vv.z, vv.w};
      #pragma unroll
      for (int qi = 0; qi < 4; ++qi) {
        #pragma unroll
        for (int ni = 0; ni < 4; ++ni) acc[qi][ni] += av[qi] * bw[ni];
      }
    }
  }

  #pragma unroll
  for (int qi = 0; qi < 4; ++qi) {
    const int tt = q0 + 4*tq + qi;
    float4 o;
    o.x = acc[qi][0]; o.y = acc[qi][1]; o.z = acc[qi][2]; o.w = acc[qi][3];
    *(float4*)&ctx[((size_t)b*Tc + tt)*Cch + h*Dc + 4*tn] = o;
  }
}

// ---------------------------------------------------------------------------
// K4: out = ctx @ Wo + bo.  Same shape/tiling as K1, plain [M][N] output.
// ---------------------------------------------------------------------------
__global__ __launch_bounds__(256) void out_gemm(
    const float* __restrict__ A,
    const float* __restrict__ W,
    const float* __restrict__ bias,
    float* __restrict__ out)
{
  const int m0 = blockIdx.y * 64;
  const int n0 = blockIdx.x * 128;

  __shared__ float aT[16][68];
  __shared__ float bN[16][132];

  const int t  = threadIdx.x;
  const int tn = t & 15;
  const int tq = t >> 4;

  float acc[4][8];
  #pragma unroll
  for (int i = 0; i < 4; ++i) {
    #pragma unroll
    for (int j = 0; j < 8; ++j) acc[i][j] = 0.f;
  }

  for (int k0 = 0; k0 < Cch; k0 += 16) {
    __syncthreads();
    {
      const int r = t >> 2, c = t & 3;
      const float4 v = *(const float4*)&A[(size_t)(m0 + r) * Cch + k0 + 4*c];
      aT[4*c + 0][r] = v.x; aT[4*c + 1][r] = v.y;
      aT[4*c + 2][r] = v.z; aT[4*c + 3][r] = v.w;
    }
    #pragma unroll
    for (int p = 0; p < 2; ++p) {
      const int id = t + 256*p;
      const int kk = id >> 5, nc = id & 31;
      const float4 v = *(const float4*)&W[(size_t)(k0 + kk) * Cch + n0 + 4*nc];
      *(float4*)&bN[kk][4*nc] = v;
    }
    __syncthreads();
    #pragma unroll
    for (int kk = 0; kk < 16; ++kk) {
      const float4 a  = *(const float4*)&aT[kk][4*tq];
      const float4 b0 = *(const float4*)&bN[kk][4*tn];
      const float4 b1 = *(const float4*)&bN[kk][64 + 4*tn];
      const float av[4] = {a.x, a.y, a.z, a.w};
      const float bw[8] = {b0.x, b0.y, b0.z, b0.w, b1.x, b1.y, b1.z, b1.w};
      #pragma unroll
      for (int qi = 0; qi < 4; ++qi) {
        #pragma unroll
        for (int ni = 0; ni < 8; ++ni) acc[qi][ni] += av[qi] * bw[ni];
      }
    }
  }

  const float4 bb0 = *(const float4*)&bias[n0 + 4*tn];
  const float4 bb1 = *(const float4*)&bias[n0 + 64 + 4*tn];
  #pragma unroll
  for (int qi = 0; qi < 4; ++qi) {
    const int m = m0 + 4*tq + qi;
    float4 o0, o1;
    o0.x = acc[qi][0] + bb0.x; o0.y = acc[qi][1] + bb0.y;
    o0.z = acc[qi][2] + bb0.z; o0.w = acc[qi][3] + bb0.w;
    o1.x = acc[qi][4] + bb1.x; o1.y = acc[qi][5] + bb1.y;
    o1.z = acc[qi][6] + bb1.z; o1.w = acc[qi][7] + bb1.w;
    *(float4*)&out[(size_t)m * Cch + n0 + 4*tn]      = o0;
    *(float4*)&out[(size_t)m * Cch + n0 + 64 + 4*tn] = o1;
  }
}

} // anonymous namespace

// ---------------------------------------------------------------------------
extern "C" void kernel_launch(void* const* d_in, const int* in_sizes, int n_in,
                              void* d_out, int out_size, void* d_ws, size_t ws_size,
                              hipStream_t stream) {
  (void)in_sizes; (void)n_in; (void)out_size; (void)ws_size;

  const float* hid  = (const float*)d_in[0];
  const float* cnt  = (const float*)d_in[1];
  const float* Wq   = (const float*)d_in[2];
  const float* bq   = (const float*)d_in[3];
  const float* Wk   = (const float*)d_in[4];
  const float* bk   = (const float*)d_in[5];
  const float* Wv   = (const float*)d_in[6];
  const float* bv   = (const float*)d_in[7];
  const float* Wo   = (const float*)d_in[8];
  const float* bo   = (const float*)d_in[9];
  const int* counter = (const int*)d_in[10];
  const int* ucb     = (const int*)d_in[11];

  float* out       = (float*)d_out;          // [B,T,C]
  float* probs     = out + BTC;              // [B,H,T,T]
  float* count_out = probs + PROBSN;         // [B,H,T,T]

  // workspace: Q | K | V | ctx, each BTC floats (needs 50.3 MB)
  float* ws = (float*)d_ws;

  qkv_gemm<<<dim3(Cch/128, (Bc*Tc)/64, 3), 256, 0, stream>>>(
      hid, Wq, bq, Wk, bk, Wv, bv, ws);

  attn_ucb<<<dim3(Tc/16, Bc*Hc), 512, 0, stream>>>(
      ws, cnt, counter, ucb, probs, count_out);

  pv_gemm<<<dim3(Tc/64, Bc*Hc), 256, 0, stream>>>(
      probs, ws + 2*BTC, ws + 3*BTC);

  out_gemm<<<dim3(Cch/128, (Bc*Tc)/64), 256, 0, stream>>>(
      ws + 3*BTC, Wo, bo, out);
}